// Round 8
// baseline (166.791 us; speedup 1.0000x reference)
//
#include <hip/hip_runtime.h>
#include <hip/hip_bf16.h>
#include <math.h>

#define SLEN 4096
#define CIN 256
#define C3 768
#define NH 4
#define HD 64
#define BATCH 4

typedef __attribute__((ext_vector_type(8))) short bf16x8;
typedef __attribute__((ext_vector_type(4))) float f32x4;
typedef __attribute__((ext_vector_type(16))) float f32x16;

typedef const __attribute__((address_space(1))) void GVoid;
typedef __attribute__((address_space(3))) void LVoid;

__device__ __forceinline__ void gl2lds16(const void* g, void* l) {
    __builtin_amdgcn_global_load_lds((GVoid*)g, (LVoid*)l, 16, 0, 0);
}

__device__ __forceinline__ short f2bf(float f) {
    union { float f; unsigned u; } v; v.f = f;
    unsigned r = v.u + 0x7fff + ((v.u >> 16) & 1);
    return (short)(r >> 16);
}

// single-instruction packed f32->bf16 (RNE) — no builtin on gfx950, inline asm per T12
__device__ __forceinline__ unsigned cvt_pk(float lo, float hi) {
    unsigned r;
    asm("v_cvt_pk_bf16_f32 %0, %1, %2" : "=v"(r) : "v"(lo), "v"(hi));
    return r;
}

// ---------------- kernel W: convert weights to bf16 ----------------
__global__ void k_convert_w(const float* __restrict__ qkvw, const float* __restrict__ projw,
                            short* __restrict__ qkvw_bf, short* __restrict__ projw_bf) {
    int i = blockIdx.x * 256 + threadIdx.x;
    if (i < C3 * CIN) qkvw_bf[i] = f2bf(qkvw[i]);
    if (i < CIN * CIN) projw_bf[i] = f2bf(projw[i]);
}

// ---------------- kernel T: x [b][c][s] f32 -> xT [b][s][c] bf16 ----------------
__global__ void k_transpose_x(const float* __restrict__ x, short* __restrict__ xT) {
    __shared__ float t[32][33];
    int b = blockIdx.z;
    int c0 = blockIdx.y * 32, s0 = blockIdx.x * 32;
    int tid = threadIdx.x;
    int r = tid >> 3, c4 = (tid & 7) * 4;
    const float* src = x + ((size_t)b * CIN + c0 + r) * SLEN + s0 + c4;
    float4 v = *reinterpret_cast<const float4*>(src);
    t[r][c4 + 0] = v.x; t[r][c4 + 1] = v.y; t[r][c4 + 2] = v.z; t[r][c4 + 3] = v.w;
    __syncthreads();
    int s_r = tid >> 3, cc = (tid & 7) * 4;
    short4 o = make_short4(f2bf(t[cc + 0][s_r]), f2bf(t[cc + 1][s_r]),
                           f2bf(t[cc + 2][s_r]), f2bf(t[cc + 3][s_r]));
    *reinterpret_cast<short4*>(xT + ((size_t)b * SLEN + s0 + s_r) * CIN + c0 + cc) = o;
}

// ---------------- kernel A: QKV GEMM + BN + SiLU -> Q, K, Vt (bf16) ----------------
// Q,K: [bh][s][d]; Vt: [bh][d][s]. Q pre-scaled by hd^-0.5 * log2(e).
__launch_bounds__(256)
__global__ void k_qkv(const short* __restrict__ xT, const short* __restrict__ wbf,
                      const float* __restrict__ g, const float* __restrict__ be,
                      const float* __restrict__ mu, const float* __restrict__ va,
                      short* __restrict__ Q, short* __restrict__ Kb, short* __restrict__ Vt) {
    int wv = threadIdx.x >> 6, l = threadIdx.x & 63, lr = l & 15, lg = l >> 4;
    int b = blockIdx.z;
    int s0 = blockIdx.x * 128 + wv * 32;
    int o0 = blockIdx.y * 64;
    f32x4 acc[2][4] = {};
    const short* aptr = xT + ((size_t)b * SLEN + s0 + lr) * CIN + lg * 8;
    const short* bptr = wbf + (size_t)(o0 + lr) * CIN + lg * 8;
#pragma unroll
    for (int k0 = 0; k0 < CIN; k0 += 32) {
        bf16x8 a0 = *(const bf16x8*)(aptr + k0);
        bf16x8 a1 = *(const bf16x8*)(aptr + 16 * CIN + k0);
#pragma unroll
        for (int oj = 0; oj < 4; oj++) {
            bf16x8 bb = *(const bf16x8*)(bptr + oj * 16 * CIN + k0);
            acc[0][oj] = __builtin_amdgcn_mfma_f32_16x16x32_bf16(a0, bb, acc[0][oj], 0, 0, 0);
            acc[1][oj] = __builtin_amdgcn_mfma_f32_16x16x32_bf16(a1, bb, acc[1][oj], 0, 0, 0);
        }
    }
    int which = o0 >> 8;          // uniform per block
    int h = (o0 & 255) >> 6;      // uniform per block
    int bh = b * NH + h;
    const float QSC = 0.125f * 1.44269504088896f;
#pragma unroll
    for (int oj = 0; oj < 4; oj++) {
        int o = o0 + oj * 16 + lr;
        float sc = g[o] * rsqrtf(va[o] + 1e-5f);
        float sh = be[o] - mu[o] * sc;
        int d = o & 63;
#pragma unroll
        for (int qi = 0; qi < 2; qi++) {
#pragma unroll
            for (int i = 0; i < 4; i++) {
                float y = acc[qi][oj][i] * sc + sh;
                float z = y / (1.f + __expf(-y));
                int s = s0 + qi * 16 + lg * 4 + i;
                if (which == 0) {
                    Q[((size_t)bh * SLEN + s) * HD + d] = f2bf(z * QSC);
                } else if (which == 1) {
                    Kb[((size_t)bh * SLEN + s) * HD + d] = f2bf(z);
                } else {
                    Vt[((size_t)bh * HD + d) * SLEN + s] = f2bf(z);
                }
            }
        }
    }
}

// ---------------- kernel ATTN: flash attention, 64 q-rows/wave (L/R halves) ----
// 4 waves/block, 64 q/wave -> 256 q/block, grid 256 (1 block/CU, 1 wave/SIMD).
// K 2-buf @ lds+0, V 4-buf @ lds+16384; async global_load_lds staging w/ pre-swizzled
// source. One set of K/V fragment ds_reads feeds BOTH q-halves (2x FLOP per LDS byte).
// S^T = mfma_32x32x16(K, Q): lane holds 32 P values for q = lane&31 per half.
__launch_bounds__(256, 1)
__global__ void k_attn(const short* __restrict__ Q, const short* __restrict__ Kg,
                       const short* __restrict__ Vg, short* __restrict__ aout) {
    __shared__ __align__(16) char lds[16384 + 32768];
    int tid = threadIdx.x;
    int wv = tid >> 6, l = tid & 63;
    int q32 = l & 31;
    int hi  = l >> 5;

    // XCD-aware bijective decode (8 XCDs): XCD k owns bh {2k, 2k+1}
    int bid = blockIdx.x;
    int xcd = bid & 7, slot = bid >> 3;
    int bh = 2 * xcd + (slot & 1);
    int q0 = (slot >> 1) * 256 + wv * 64;

    const short* kg = Kg + (size_t)bh * SLEN * HD;
    const short* vg = Vg + (size_t)bh * HD * SLEN;

    // Q B-fragments for both halves: rows qL = q0+q32, qR = q0+32+q32
    bf16x8 qfL[4], qfR[4];
    {
        const short* qb = Q + ((size_t)bh * SLEN + q0 + q32) * HD + hi * 8;
        qfL[0] = *(const bf16x8*)(qb);
        qfL[1] = *(const bf16x8*)(qb + 16);
        qfL[2] = *(const bf16x8*)(qb + 32);
        qfL[3] = *(const bf16x8*)(qb + 48);
        const short* qb2 = qb + 32 * HD;
        qfR[0] = *(const bf16x8*)(qb2);
        qfR[1] = *(const bf16x8*)(qb2 + 16);
        qfR[2] = *(const bf16x8*)(qb2 + 32);
        qfR[3] = *(const bf16x8*)(qb2 + 48);
    }

    // ones A-fragment for the row-sum MFMA
    bf16x8 ones;
#pragma unroll
    for (int e = 0; e < 8; ++e) ones[e] = (short)0x3F80;

    f32x16 oaccL0 = {}, oaccL1 = {}, oaccR0 = {}, oaccR1 = {}, saccL = {}, saccR = {};
    float mrunL = 0.0f, mrunR = 0.0f, bAL = 0.0f, bAR = 0.0f, bBL = 0.0f, bBR = 0.0f;

    // ---- async staging geometry (same as r6): wave wv stages rows wv*16..wv*16+15 ----
    int colsw = (((l & 7) ^ (l >> 3)) << 4);                  // bytes
    const char* kgB = (const char*)kg;
    const char* vgB = (const char*)vg;
    int ksrc = (wv * 16 + (l >> 3)) * 128 + colsw;
    int vsrc = (wv * 16 + (l >> 3)) * 8192 + colsw;
    int wdst = wv * 2048;

#define STAGE(T, KB, VB) do { \
    gl2lds16(kgB + (size_t)(T) * 8192 + ksrc,          lds + (KB) * 8192 + wdst); \
    gl2lds16(kgB + (size_t)(T) * 8192 + ksrc + 1024,   lds + (KB) * 8192 + wdst + 1024); \
    gl2lds16(vgB + (size_t)(T) * 128 + vsrc,           lds + 16384 + (VB) * 8192 + wdst); \
    gl2lds16(vgB + (size_t)(T) * 128 + vsrc + 65536,   lds + 16384 + (VB) * 8192 + wdst + 1024); \
} while (0)

#define VMBAR() do { \
    asm volatile("s_waitcnt vmcnt(0) lgkmcnt(0)" ::: "memory"); \
    __builtin_amdgcn_s_barrier(); \
    asm volatile("" ::: "memory"); \
} while (0)

    // per-lane read offsets (bytes within a 64x64-short tile); serve K and V
    int swz = (l & 7) << 4;
    int a0 = q32 * 128 + ((0 * 32 + hi * 16) ^ swz);
    int a1 = q32 * 128 + ((1 * 32 + hi * 16) ^ swz);
    int a2 = q32 * 128 + ((2 * 32 + hi * 16) ^ swz);
    int a3 = q32 * 128 + ((3 * 32 + hi * 16) ^ swz);

#define MM(A, B, C) __builtin_amdgcn_mfma_f32_32x32x16_bf16(A, B, C, 0, 0, 0)

// QK^T both halves from K buffer KB; accumulators bias-initialized with -mrun{L,R}
#define QKT2(KB, DL0, DL1, DR0, DR1, BL, BR) do { \
    BL = mrunL; BR = mrunR; \
    float nbl_ = -mrunL, nbr_ = -mrunR; \
    _Pragma("unroll") for (int r_ = 0; r_ < 16; ++r_) { \
        DL0[r_] = nbl_; DL1[r_] = nbl_; DR0[r_] = nbr_; DR1[r_] = nbr_; } \
    __builtin_amdgcn_s_setprio(1); \
    { \
        bf16x8 k0_, k1_; \
        k0_ = *(const bf16x8*)(lds + a0 + (KB) * 8192); \
        k1_ = *(const bf16x8*)(lds + a0 + (KB) * 8192 + 4096); \
        DL0 = MM(k0_, qfL[0], DL0); DL1 = MM(k1_, qfL[0], DL1); \
        DR0 = MM(k0_, qfR[0], DR0); DR1 = MM(k1_, qfR[0], DR1); \
        k0_ = *(const bf16x8*)(lds + a1 + (KB) * 8192); \
        k1_ = *(const bf16x8*)(lds + a1 + (KB) * 8192 + 4096); \
        DL0 = MM(k0_, qfL[1], DL0); DL1 = MM(k1_, qfL[1], DL1); \
        DR0 = MM(k0_, qfR[1], DR0); DR1 = MM(k1_, qfR[1], DR1); \
        k0_ = *(const bf16x8*)(lds + a2 + (KB) * 8192); \
        k1_ = *(const bf16x8*)(lds + a2 + (KB) * 8192 + 4096); \
        DL0 = MM(k0_, qfL[2], DL0); DL1 = MM(k1_, qfL[2], DL1); \
        DR0 = MM(k0_, qfR[2], DR0); DR1 = MM(k1_, qfR[2], DR1); \
        k0_ = *(const bf16x8*)(lds + a3 + (KB) * 8192); \
        k1_ = *(const bf16x8*)(lds + a3 + (KB) * 8192 + 4096); \
        DL0 = MM(k0_, qfL[3], DL0); DL1 = MM(k1_, qfL[3], DL1); \
        DR0 = MM(k0_, qfR[3], DR0); DR1 = MM(k1_, qfR[3], DR1); \
    } \
    __builtin_amdgcn_s_setprio(0); \
} while (0)

// one 32-k PV chunk, both halves share V fragments
#define PVKC2(AK, SL, SR, BASE, VB) do { \
    unsigned L0_ = cvt_pk(SL[(BASE) + 0], SL[(BASE) + 1]); \
    unsigned L1_ = cvt_pk(SL[(BASE) + 2], SL[(BASE) + 3]); \
    unsigned L2_ = cvt_pk(SL[(BASE) + 4], SL[(BASE) + 5]); \
    unsigned L3_ = cvt_pk(SL[(BASE) + 6], SL[(BASE) + 7]); \
    asm volatile("v_permlane32_swap_b32 %0, %1" : "+v"(L0_), "+v"(L2_)); \
    asm volatile("v_permlane32_swap_b32 %0, %1" : "+v"(L1_), "+v"(L3_)); \
    unsigned R0_ = cvt_pk(SR[(BASE) + 0], SR[(BASE) + 1]); \
    unsigned R1_ = cvt_pk(SR[(BASE) + 2], SR[(BASE) + 3]); \
    unsigned R2_ = cvt_pk(SR[(BASE) + 4], SR[(BASE) + 5]); \
    unsigned R3_ = cvt_pk(SR[(BASE) + 6], SR[(BASE) + 7]); \
    asm volatile("v_permlane32_swap_b32 %0, %1" : "+v"(R0_), "+v"(R2_)); \
    asm volatile("v_permlane32_swap_b32 %0, %1" : "+v"(R1_), "+v"(R3_)); \
    union { bf16x8 v; unsigned u[4]; } pfL_, pfR_; \
    pfL_.u[0] = L0_; pfL_.u[1] = L1_; pfL_.u[2] = L2_; pfL_.u[3] = L3_; \
    pfR_.u[0] = R0_; pfR_.u[1] = R1_; pfR_.u[2] = R2_; pfR_.u[3] = R3_; \
    bf16x8 v0_ = *(const bf16x8*)(lds + (AK) + 16384 + (VB) * 8192); \
    bf16x8 v1_ = *(const bf16x8*)(lds + (AK) + 16384 + (VB) * 8192 + 4096); \
    oaccL0 = MM(v0_, pfL_.v, oaccL0); oaccL1 = MM(v1_, pfL_.v, oaccL1); \
    oaccR0 = MM(v0_, pfR_.v, oaccR0); oaccR1 = MM(v1_, pfR_.v, oaccR1); \
    saccL = MM(ones, pfL_.v, saccL);  saccR = MM(ones, pfR_.v, saccR); \
} while (0)

// softmax both halves (biased scores) + merged PV from V buffer VB
#define SMPV2(VB, SL0, SL1, SR0, SR1, BL, BR) do { \
    float paL_ = SL0[0], pbL_ = SL0[8], pcL_ = SL1[0], pdL_ = SL1[8]; \
    float paR_ = SR0[0], pbR_ = SR0[8], pcR_ = SR1[0], pdR_ = SR1[8]; \
    _Pragma("unroll") for (int r_ = 1; r_ < 8; ++r_) { \
        paL_ = fmaxf(paL_, SL0[r_]); pbL_ = fmaxf(pbL_, SL0[8 + r_]); \
        pcL_ = fmaxf(pcL_, SL1[r_]); pdL_ = fmaxf(pdL_, SL1[8 + r_]); \
        paR_ = fmaxf(paR_, SR0[r_]); pbR_ = fmaxf(pbR_, SR0[8 + r_]); \
        pcR_ = fmaxf(pcR_, SR1[r_]); pdR_ = fmaxf(pdR_, SR1[8 + r_]); \
    } \
    float pmsL_ = fmaxf(fmaxf(paL_, pbL_), fmaxf(pcL_, pdL_)); \
    float pmsR_ = fmaxf(fmaxf(paR_, pbR_), fmaxf(pcR_, pdR_)); \
    { float c1_ = pmsL_, c2_ = pmsL_; \
      asm volatile("" : "+v"(c2_)); \
      asm volatile("v_permlane32_swap_b32 %0, %1" : "+v"(c1_), "+v"(c2_)); \
      pmsL_ = fmaxf(c1_, c2_); } \
    { float c1_ = pmsR_, c2_ = pmsR_; \
      asm volatile("" : "+v"(c2_)); \
      asm volatile("v_permlane32_swap_b32 %0, %1" : "+v"(c1_), "+v"(c2_)); \
      pmsR_ = fmaxf(c1_, c2_); } \
    float dbL_ = mrunL - (BL), dbR_ = mrunR - (BR); \
    if (!__all((pmsL_ <= dbL_ + 10.0f) && (pmsR_ <= dbR_ + 10.0f))) { \
        float mnL_ = fmaxf(mrunL, pmsL_ + (BL)); \
        float alL_ = __builtin_amdgcn_exp2f(mrunL - mnL_); \
        float mnR_ = fmaxf(mrunR, pmsR_ + (BR)); \
        float alR_ = __builtin_amdgcn_exp2f(mrunR - mnR_); \
        _Pragma("unroll") for (int r_ = 0; r_ < 16; ++r_) { \
            oaccL0[r_] *= alL_; oaccL1[r_] *= alL_; \
            oaccR0[r_] *= alR_; oaccR1[r_] *= alR_; } \
        saccL[0] *= alL_; saccR[0] *= alR_; \
        mrunL = mnL_; dbL_ = mnL_ - (BL); \
        mrunR = mnR_; dbR_ = mnR_ - (BR); \
    } \
    if (__all((dbL_ == 0.0f) && (dbR_ == 0.0f))) { \
        _Pragma("unroll") for (int r_ = 0; r_ < 16; ++r_) { \
            SL0[r_] = __builtin_amdgcn_exp2f(SL0[r_]); \
            SL1[r_] = __builtin_amdgcn_exp2f(SL1[r_]); \
            SR0[r_] = __builtin_amdgcn_exp2f(SR0[r_]); \
            SR1[r_] = __builtin_amdgcn_exp2f(SR1[r_]); } \
    } else { \
        _Pragma("unroll") for (int r_ = 0; r_ < 16; ++r_) { \
            SL0[r_] = __builtin_amdgcn_exp2f(SL0[r_] - dbL_); \
            SL1[r_] = __builtin_amdgcn_exp2f(SL1[r_] - dbL_); \
            SR0[r_] = __builtin_amdgcn_exp2f(SR0[r_] - dbR_); \
            SR1[r_] = __builtin_amdgcn_exp2f(SR1[r_] - dbR_); } \
    } \
    __builtin_amdgcn_s_setprio(1); \
    PVKC2(a0, SL0, SR0, 0, VB); \
    PVKC2(a1, SL0, SR0, 8, VB); \
    PVKC2(a2, SL1, SR1, 0, VB); \
    PVKC2(a3, SL1, SR1, 8, VB); \
    __builtin_amdgcn_s_setprio(0); \
} while (0)

    f32x16 sAL0, sAL1, sAR0, sAR1, sBL0, sBL1, sBR0, sBR1;

    // prologue: stage 0; drain; stage 1 + QK(0)->A; drain
    STAGE(0, 0, 0);
    VMBAR();
    STAGE(1, 1, 1);
    QKT2(0, sAL0, sAL1, sAR0, sAR1, bAL, bAR);
    VMBAR();

    // steady state: tiles 1..60, unroll 4 (all buffer indices literal)
    for (int j = 0; j < 15; ++j) {
        STAGE(4 * j + 2, 0, 2); QKT2(1, sBL0, sBL1, sBR0, sBR1, bBL, bBR); SMPV2(0, sAL0, sAL1, sAR0, sAR1, bAL, bAR); VMBAR();
        STAGE(4 * j + 3, 1, 3); QKT2(0, sAL0, sAL1, sAR0, sAR1, bAL, bAR); SMPV2(1, sBL0, sBL1, sBR0, sBR1, bBL, bBR); VMBAR();
        STAGE(4 * j + 4, 0, 0); QKT2(1, sBL0, sBL1, sBR0, sBR1, bBL, bBR); SMPV2(2, sAL0, sAL1, sAR0, sAR1, bAL, bAR); VMBAR();
        STAGE(4 * j + 5, 1, 1); QKT2(0, sAL0, sAL1, sAR0, sAR1, bAL, bAR); SMPV2(3, sBL0, sBL1, sBR0, sBR1, bBL, bBR); VMBAR();
    }
    // t = 61
    STAGE(62, 0, 2); QKT2(1, sBL0, sBL1, sBR0, sBR1, bBL, bBR); SMPV2(0, sAL0, sAL1, sAR0, sAR1, bAL, bAR); VMBAR();
    // t = 62
    STAGE(63, 1, 3); QKT2(0, sAL0, sAL1, sAR0, sAR1, bAL, bAR); SMPV2(1, sBL0, sBL1, sBR0, sBR1, bBL, bBR); VMBAR();
    // t = 63
    QKT2(1, sBL0, sBL1, sBR0, sBR1, bBL, bBR); SMPV2(2, sAL0, sAL1, sAR0, sAR1, bAL, bAR);
    SMPV2(3, sBL0, sBL1, sBR0, sBR1, bBL, bBR);

    // ---- epilogue: O^T/l -> aout [b][s][c] bf16, both halves ----
    float invL = 1.f / saccL[0];
    float invR = 1.f / saccR[0];
    int b = bh >> 2, h = bh & 3;
    short* obL = aout + ((size_t)b * SLEN + q0 + q32) * CIN + h * HD;
    short* obR = obL + 32 * CIN;
#pragma unroll
    for (int g4 = 0; g4 < 4; ++g4) {
        uint2 st0, st1;
        st0.x = cvt_pk(oaccL0[4 * g4 + 0] * invL, oaccL0[4 * g4 + 1] * invL);
        st0.y = cvt_pk(oaccL0[4 * g4 + 2] * invL, oaccL0[4 * g4 + 3] * invL);
        st1.x = cvt_pk(oaccL1[4 * g4 + 0] * invL, oaccL1[4 * g4 + 1] * invL);
        st1.y = cvt_pk(oaccL1[4 * g4 + 2] * invL, oaccL1[4 * g4 + 3] * invL);
        *(uint2*)(obL + 8 * g4 + 4 * hi) = st0;
        *(uint2*)(obL + 32 + 8 * g4 + 4 * hi) = st1;
        st0.x = cvt_pk(oaccR0[4 * g4 + 0] * invR, oaccR0[4 * g4 + 1] * invR);
        st0.y = cvt_pk(oaccR0[4 * g4 + 2] * invR, oaccR0[4 * g4 + 3] * invR);
        st1.x = cvt_pk(oaccR1[4 * g4 + 0] * invR, oaccR1[4 * g4 + 1] * invR);
        st1.y = cvt_pk(oaccR1[4 * g4 + 2] * invR, oaccR1[4 * g4 + 3] * invR);
        *(uint2*)(obR + 8 * g4 + 4 * hi) = st0;
        *(uint2*)(obR + 32 + 8 * g4 + 4 * hi) = st1;
    }
#undef STAGE
#undef VMBAR
#undef MM
#undef QKT2
#undef PVKC2
#undef SMPV2
}

// ---------------- kernel C: proj GEMM + BN + SiLU -> fp32 out ----------------
__launch_bounds__(256)
__global__ void k_proj(const short* __restrict__ aout, const short* __restrict__ wbf,
                       const float* __restrict__ g, const float* __restrict__ be,
                       const float* __restrict__ mu, const float* __restrict__ va,
                       float* __restrict__ out) {
    int wv = threadIdx.x >> 6, l = threadIdx.x & 63, lr = l & 15, lg = l >> 4;
    int b = blockIdx.z;
    int s0 = blockIdx.x * 128 + wv * 32;
    int o0 = blockIdx.y * 64;
    f32x4 acc[2][4] = {};
    const short* aptr = aout + ((size_t)b * SLEN + s0 + lr) * CIN + lg * 8;
    const short* bptr = wbf + (size_t)(o0 + lr) * CIN + lg * 8;
#pragma unroll
    for (int k0 = 0; k0 < CIN; k0 += 32) {
        bf16x8 a0 = *(const bf16x8*)(aptr + k0);
        bf16x8 a1 = *(const bf16x8*)(aptr + 16 * CIN + k0);
#pragma unroll
        for (int oj = 0; oj < 4; oj++) {
            bf16x8 bb = *(const bf16x8*)(bptr + oj * 16 * CIN + k0);
            acc[0][oj] = __builtin_amdgcn_mfma_f32_16x16x32_bf16(a0, bb, acc[0][oj], 0, 0, 0);
            acc[1][oj] = __builtin_amdgcn_mfma_f32_16x16x32_bf16(a1, bb, acc[1][oj], 0, 0, 0);
        }
    }
#pragma unroll
    for (int oj = 0; oj < 4; oj++) {
        int o = o0 + oj * 16 + lr;
        float sc = g[o] * rsqrtf(va[o] + 1e-5f);
        float sh = be[o] - mu[o] * sc;
#pragma unroll
        for (int qi = 0; qi < 2; qi++) {
            float4 st;
            float* stp = &st.x;
#pragma unroll
            for (int i = 0; i < 4; i++) {
                float y = acc[qi][oj][i] * sc + sh;
                stp[i] = y / (1.f + __expf(-y));
            }
            int s = s0 + qi * 16 + lg * 4;
            *reinterpret_cast<float4*>(out + ((size_t)b * CIN + o) * SLEN + s) = st;
        }
    }
}

extern "C" void kernel_launch(void* const* d_in, const int* in_sizes, int n_in,
                              void* d_out, int out_size, void* d_ws, size_t ws_size,
                              hipStream_t stream) {
    const float* x    = (const float*)d_in[0];
    const float* qkvw = (const float*)d_in[1];
    const float* qg   = (const float*)d_in[2];
    const float* qbe  = (const float*)d_in[3];
    const float* qmu  = (const float*)d_in[4];
    const float* qva  = (const float*)d_in[5];
    const float* pw   = (const float*)d_in[6];
    const float* pg   = (const float*)d_in[7];
    const float* pbe  = (const float*)d_in[8];
    const float* pmu  = (const float*)d_in[9];
    const float* pva  = (const float*)d_in[10];
    float* out = (float*)d_out;

    char* ws = (char*)d_ws;
    short* xT       = (short*)(ws);                 // 8,388,608 B
    short* qkvw_bf  = (short*)(ws + 8388608);       //   393,216 B
    short* projw_bf = (short*)(ws + 8781824);       //   131,072 B
    short* Qb       = (short*)(ws + 8912896);       // 8,388,608 B
    short* Kb       = (short*)(ws + 17301504);      // 8,388,608 B
    short* Vt       = (short*)(ws + 25690112);      // 8,388,608 B
    short* aout     = (short*)(ws + 34078720);      // 8,388,608 B

    k_convert_w<<<768, 256, 0, stream>>>(qkvw, pw, qkvw_bf, projw_bf);
    k_transpose_x<<<dim3(128, 8, 4), 256, 0, stream>>>(x, xT);
    k_qkv<<<dim3(32, 12, 4), 256, 0, stream>>>(xT, qkvw_bf, qg, qbe, qmu, qva, Qb, Kb, Vt);
    k_attn<<<256, 256, 0, stream>>>(Qb, Kb, Vt, aout);
    k_proj<<<dim3(32, 4, 4), 256, 0, stream>>>(aout, projw_bf, pg, pbe, pmu, pva, out);
}

// Round 9
// 160.202 us; speedup vs baseline: 1.0411x; 1.0411x over previous
//
#include <hip/hip_runtime.h>
#include <hip/hip_bf16.h>
#include <math.h>

#define SLEN 4096
#define CIN 256
#define C3 768
#define NH 4
#define HD 64
#define BATCH 4

typedef __attribute__((ext_vector_type(8))) short bf16x8;
typedef __attribute__((ext_vector_type(4))) float f32x4;
typedef __attribute__((ext_vector_type(16))) float f32x16;

typedef const __attribute__((address_space(1))) void GVoid;
typedef __attribute__((address_space(3))) void LVoid;

__device__ __forceinline__ void gl2lds16(const void* g, void* l) {
    __builtin_amdgcn_global_load_lds((GVoid*)g, (LVoid*)l, 16, 0, 0);
}

__device__ __forceinline__ short f2bf(float f) {
    union { float f; unsigned u; } v; v.f = f;
    unsigned r = v.u + 0x7fff + ((v.u >> 16) & 1);
    return (short)(r >> 16);
}

// single-instruction packed f32->bf16 (RNE) — no builtin on gfx950, inline asm per T12
__device__ __forceinline__ unsigned cvt_pk(float lo, float hi) {
    unsigned r;
    asm("v_cvt_pk_bf16_f32 %0, %1, %2" : "=v"(r) : "v"(lo), "v"(hi));
    return r;
}

// ---------------- kernel W: convert weights to bf16 ----------------
__global__ void k_convert_w(const float* __restrict__ qkvw, const float* __restrict__ projw,
                            short* __restrict__ qkvw_bf, short* __restrict__ projw_bf) {
    int i = blockIdx.x * 256 + threadIdx.x;
    if (i < C3 * CIN) qkvw_bf[i] = f2bf(qkvw[i]);
    if (i < CIN * CIN) projw_bf[i] = f2bf(projw[i]);
}

// ---------------- kernel T: x [b][c][s] f32 -> xT [b][s][c] bf16 ----------------
__global__ void k_transpose_x(const float* __restrict__ x, short* __restrict__ xT) {
    __shared__ float t[32][33];
    int b = blockIdx.z;
    int c0 = blockIdx.y * 32, s0 = blockIdx.x * 32;
    int tid = threadIdx.x;
    int r = tid >> 3, c4 = (tid & 7) * 4;
    const float* src = x + ((size_t)b * CIN + c0 + r) * SLEN + s0 + c4;
    float4 v = *reinterpret_cast<const float4*>(src);
    t[r][c4 + 0] = v.x; t[r][c4 + 1] = v.y; t[r][c4 + 2] = v.z; t[r][c4 + 3] = v.w;
    __syncthreads();
    int s_r = tid >> 3, cc = (tid & 7) * 4;
    short4 o = make_short4(f2bf(t[cc + 0][s_r]), f2bf(t[cc + 1][s_r]),
                           f2bf(t[cc + 2][s_r]), f2bf(t[cc + 3][s_r]));
    *reinterpret_cast<short4*>(xT + ((size_t)b * SLEN + s0 + s_r) * CIN + c0 + cc) = o;
}

// ---------------- kernel A: QKV GEMM + BN + SiLU -> Q, K, Vt (bf16) ----------------
// Q,K: [bh][s][d]; Vt: [bh][d][s]. Q pre-scaled by hd^-0.5 * log2(e).
__launch_bounds__(256)
__global__ void k_qkv(const short* __restrict__ xT, const short* __restrict__ wbf,
                      const float* __restrict__ g, const float* __restrict__ be,
                      const float* __restrict__ mu, const float* __restrict__ va,
                      short* __restrict__ Q, short* __restrict__ Kb, short* __restrict__ Vt) {
    int wv = threadIdx.x >> 6, l = threadIdx.x & 63, lr = l & 15, lg = l >> 4;
    int b = blockIdx.z;
    int s0 = blockIdx.x * 128 + wv * 32;
    int o0 = blockIdx.y * 64;
    f32x4 acc[2][4] = {};
    const short* aptr = xT + ((size_t)b * SLEN + s0 + lr) * CIN + lg * 8;
    const short* bptr = wbf + (size_t)(o0 + lr) * CIN + lg * 8;
#pragma unroll
    for (int k0 = 0; k0 < CIN; k0 += 32) {
        bf16x8 a0 = *(const bf16x8*)(aptr + k0);
        bf16x8 a1 = *(const bf16x8*)(aptr + 16 * CIN + k0);
#pragma unroll
        for (int oj = 0; oj < 4; oj++) {
            bf16x8 bb = *(const bf16x8*)(bptr + oj * 16 * CIN + k0);
            acc[0][oj] = __builtin_amdgcn_mfma_f32_16x16x32_bf16(a0, bb, acc[0][oj], 0, 0, 0);
            acc[1][oj] = __builtin_amdgcn_mfma_f32_16x16x32_bf16(a1, bb, acc[1][oj], 0, 0, 0);
        }
    }
    int which = o0 >> 8;          // uniform per block
    int h = (o0 & 255) >> 6;      // uniform per block
    int bh = b * NH + h;
    const float QSC = 0.125f * 1.44269504088896f;
#pragma unroll
    for (int oj = 0; oj < 4; oj++) {
        int o = o0 + oj * 16 + lr;
        float sc = g[o] * rsqrtf(va[o] + 1e-5f);
        float sh = be[o] - mu[o] * sc;
        int d = o & 63;
#pragma unroll
        for (int qi = 0; qi < 2; qi++) {
#pragma unroll
            for (int i = 0; i < 4; i++) {
                float y = acc[qi][oj][i] * sc + sh;
                float z = y / (1.f + __expf(-y));
                int s = s0 + qi * 16 + lg * 4 + i;
                if (which == 0) {
                    Q[((size_t)bh * SLEN + s) * HD + d] = f2bf(z * QSC);
                } else if (which == 1) {
                    Kb[((size_t)bh * SLEN + s) * HD + d] = f2bf(z);
                } else {
                    Vt[((size_t)bh * HD + d) * SLEN + s] = f2bf(z);
                }
            }
        }
    }
}

// ---------------- kernel ATTN: flash attention, pipelined swapped-QK^T ----
// 4 waves/block, 32 q-rows/wave, KVBLK=64. K 4-buf @ lds+0, V 4-buf @ lds+32768.
// Staging via global_load_lds w/ pre-swizzled source. TWO tiles per barrier section:
// QKT(t), QKT(t+1), SMPV(t), SMPV(t+1) between syncs (in-wave MFMA/VALU overlap).
// Row-sum on VALU (srun), not MFMA. XCD-aware decode. Bias-init accumulators.
__launch_bounds__(256, 2)
__global__ void k_attn(const short* __restrict__ Q, const short* __restrict__ Kg,
                       const short* __restrict__ Vg, short* __restrict__ aout) {
    __shared__ __align__(16) char lds[32768 + 32768];
    int tid = threadIdx.x;
    int wv = tid >> 6, l = tid & 63;
    int q32 = l & 31;           // q within wave tile (and k-row / d-row for A-frags)
    int hi  = l >> 5;

    // XCD-aware bijective decode (8 XCDs, dispatch round-robin bid%8)
    int bid = blockIdx.x;
    int xcd = bid & 7, slot = bid >> 3;
    int bh = 2 * xcd + (slot & 1);
    int q0 = (slot >> 1) * 128 + wv * 32;

    const short* kg = Kg + (size_t)bh * SLEN * HD;
    const short* vg = Vg + (size_t)bh * HD * SLEN;

    // Q B-fragments: rows q=lane&31, frag jd holds d = jd*16 + hi*8 + 0..7
    bf16x8 qf[4];
    {
        const short* qb = Q + ((size_t)bh * SLEN + q0 + q32) * HD + hi * 8;
        qf[0] = *(const bf16x8*)(qb);
        qf[1] = *(const bf16x8*)(qb + 16);
        qf[2] = *(const bf16x8*)(qb + 32);
        qf[3] = *(const bf16x8*)(qb + 48);
    }

    f32x16 oacc0 = {}, oacc1 = {};
    float mrun = 0.0f, bA = 0.0f, bB = 0.0f, srun = 0.0f;

    // ---- async staging geometry: wave wv stages rows wv*16..wv*16+15 ----
    int colsw = (((l & 7) ^ (l >> 3)) << 4);                  // bytes
    const char* kgB = (const char*)kg;
    const char* vgB = (const char*)vg;
    int ksrc = (wv * 16 + (l >> 3)) * 128 + colsw;
    int vsrc = (wv * 16 + (l >> 3)) * 8192 + colsw;
    int wdst = wv * 2048;                                     // wave-uniform LDS dest

#define STAGE(T, KB, VB) do { \
    gl2lds16(kgB + (size_t)(T) * 8192 + ksrc,          lds + (KB) * 8192 + wdst); \
    gl2lds16(kgB + (size_t)(T) * 8192 + ksrc + 1024,   lds + (KB) * 8192 + wdst + 1024); \
    gl2lds16(vgB + (size_t)(T) * 128 + vsrc,           lds + 32768 + (VB) * 8192 + wdst); \
    gl2lds16(vgB + (size_t)(T) * 128 + vsrc + 65536,   lds + 32768 + (VB) * 8192 + wdst + 1024); \
} while (0)

#define VMBAR() do { \
    asm volatile("s_waitcnt vmcnt(0)" ::: "memory"); \
    __builtin_amdgcn_s_barrier(); \
    asm volatile("" ::: "memory"); \
} while (0)

    // per-lane read offsets (bytes within a 64x64-short tile); serve K and V
    int swz = (l & 7) << 4;
    int a0 = q32 * 128 + ((0 * 32 + hi * 16) ^ swz);
    int a1 = q32 * 128 + ((1 * 32 + hi * 16) ^ swz);
    int a2 = q32 * 128 + ((2 * 32 + hi * 16) ^ swz);
    int a3 = q32 * 128 + ((3 * 32 + hi * 16) ^ swz);

// QK^T for one tile from K buffer KB, accumulators bias-initialized with -mrun
#define QKT(KB, D0, D1, BSET) do { \
    BSET = mrun; \
    float nb_ = -mrun; \
    _Pragma("unroll") for (int r_ = 0; r_ < 16; ++r_) { D0[r_] = nb_; D1[r_] = nb_; } \
    __builtin_amdgcn_s_setprio(1); \
    { \
        bf16x8 k0_, k1_; \
        k0_ = *(const bf16x8*)(lds + a0 + (KB) * 8192); \
        k1_ = *(const bf16x8*)(lds + a0 + (KB) * 8192 + 4096); \
        D0 = __builtin_amdgcn_mfma_f32_32x32x16_bf16(k0_, qf[0], D0, 0, 0, 0); \
        D1 = __builtin_amdgcn_mfma_f32_32x32x16_bf16(k1_, qf[0], D1, 0, 0, 0); \
        k0_ = *(const bf16x8*)(lds + a1 + (KB) * 8192); \
        k1_ = *(const bf16x8*)(lds + a1 + (KB) * 8192 + 4096); \
        D0 = __builtin_amdgcn_mfma_f32_32x32x16_bf16(k0_, qf[1], D0, 0, 0, 0); \
        D1 = __builtin_amdgcn_mfma_f32_32x32x16_bf16(k1_, qf[1], D1, 0, 0, 0); \
        k0_ = *(const bf16x8*)(lds + a2 + (KB) * 8192); \
        k1_ = *(const bf16x8*)(lds + a2 + (KB) * 8192 + 4096); \
        D0 = __builtin_amdgcn_mfma_f32_32x32x16_bf16(k0_, qf[2], D0, 0, 0, 0); \
        D1 = __builtin_amdgcn_mfma_f32_32x32x16_bf16(k1_, qf[2], D1, 0, 0, 0); \
        k0_ = *(const bf16x8*)(lds + a3 + (KB) * 8192); \
        k1_ = *(const bf16x8*)(lds + a3 + (KB) * 8192 + 4096); \
        D0 = __builtin_amdgcn_mfma_f32_32x32x16_bf16(k0_, qf[3], D0, 0, 0, 0); \
        D1 = __builtin_amdgcn_mfma_f32_32x32x16_bf16(k1_, qf[3], D1, 0, 0, 0); \
    } \
    __builtin_amdgcn_s_setprio(0); \
} while (0)

// one 32-k PV chunk: scores SV[BASE..BASE+7], V cols via addr reg AK, buffer VB
#define PVKC(AK, SV, BASE, VB) do { \
    unsigned A0_ = cvt_pk(SV[(BASE) + 0], SV[(BASE) + 1]); \
    unsigned A1_ = cvt_pk(SV[(BASE) + 2], SV[(BASE) + 3]); \
    unsigned A2_ = cvt_pk(SV[(BASE) + 4], SV[(BASE) + 5]); \
    unsigned A3_ = cvt_pk(SV[(BASE) + 6], SV[(BASE) + 7]); \
    asm volatile("v_permlane32_swap_b32 %0, %1" : "+v"(A0_), "+v"(A2_)); \
    asm volatile("v_permlane32_swap_b32 %0, %1" : "+v"(A1_), "+v"(A3_)); \
    union { bf16x8 v; unsigned u[4]; } pf_; \
    pf_.u[0] = A0_; pf_.u[1] = A1_; pf_.u[2] = A2_; pf_.u[3] = A3_; \
    bf16x8 v0_ = *(const bf16x8*)(lds + (AK) + 32768 + (VB) * 8192); \
    bf16x8 v1_ = *(const bf16x8*)(lds + (AK) + 32768 + (VB) * 8192 + 4096); \
    oacc0 = __builtin_amdgcn_mfma_f32_32x32x16_bf16(v0_, pf_.v, oacc0, 0, 0, 0); \
    oacc1 = __builtin_amdgcn_mfma_f32_32x32x16_bf16(v1_, pf_.v, oacc1, 0, 0, 0); \
} while (0)

// softmax (biased scores: s = S - BSET) + VALU row-sum + PV from V buffer VB
#define SMPV(VB, S0, S1, BSET) do { \
    float pa_ = S0[0], pb_ = S0[8], pc_ = S1[0], pd_ = S1[8]; \
    _Pragma("unroll") for (int r_ = 1; r_ < 8; ++r_) { \
        pa_ = fmaxf(pa_, S0[r_]); pb_ = fmaxf(pb_, S0[8 + r_]); \
        pc_ = fmaxf(pc_, S1[r_]); pd_ = fmaxf(pd_, S1[8 + r_]); \
    } \
    float pms_ = fmaxf(fmaxf(pa_, pb_), fmaxf(pc_, pd_)); \
    float c1_ = pms_, c2_ = pms_; \
    asm volatile("" : "+v"(c2_)); /* force distinct register */ \
    asm volatile("v_permlane32_swap_b32 %0, %1" : "+v"(c1_), "+v"(c2_)); \
    pms_ = fmaxf(c1_, c2_); \
    float db_ = mrun - (BSET); \
    if (!__all(pms_ <= db_ + 10.0f)) { \
        float mn_ = fmaxf(mrun, pms_ + (BSET)); \
        float al_ = __builtin_amdgcn_exp2f(mrun - mn_); \
        _Pragma("unroll") for (int r_ = 0; r_ < 16; ++r_) { oacc0[r_] *= al_; oacc1[r_] *= al_; } \
        srun *= al_; \
        mrun = mn_; db_ = mn_ - (BSET); \
    } \
    if (__all(db_ == 0.0f)) { \
        _Pragma("unroll") for (int r_ = 0; r_ < 16; ++r_) { \
            S0[r_] = __builtin_amdgcn_exp2f(S0[r_]); \
            S1[r_] = __builtin_amdgcn_exp2f(S1[r_]); \
        } \
    } else { \
        _Pragma("unroll") for (int r_ = 0; r_ < 16; ++r_) { \
            S0[r_] = __builtin_amdgcn_exp2f(S0[r_] - db_); \
            S1[r_] = __builtin_amdgcn_exp2f(S1[r_] - db_); \
        } \
    } \
    { \
        float t0_ = 0.f, t1_ = 0.f, t2_ = 0.f, t3_ = 0.f; \
        _Pragma("unroll") for (int r_ = 0; r_ < 8; ++r_) { \
            t0_ += S0[r_]; t1_ += S0[8 + r_]; t2_ += S1[r_]; t3_ += S1[8 + r_]; \
        } \
        srun += (t0_ + t1_) + (t2_ + t3_); \
    } \
    __builtin_amdgcn_s_setprio(1); \
    PVKC(a0, S0, 0, VB); \
    PVKC(a1, S0, 8, VB); \
    PVKC(a2, S1, 0, VB); \
    PVKC(a3, S1, 8, VB); \
    __builtin_amdgcn_s_setprio(0); \
} while (0)

    f32x16 sA0, sA1, sB0, sB1;

    // prologue: stage tiles 0,1 (bufs 0,1); drain
    STAGE(0, 0, 0);
    STAGE(1, 1, 1);
    VMBAR();

    // steady state: 2 tiles per barrier section, buffers cycle 0123
    for (int m = 0; m < 15; ++m) {
        int t = 4 * m;
        STAGE(t + 2, 2, 2); STAGE(t + 3, 3, 3);
        QKT(0, sA0, sA1, bA); QKT(1, sB0, sB1, bB);
        SMPV(0, sA0, sA1, bA); SMPV(1, sB0, sB1, bB);
        VMBAR();
        STAGE(t + 4, 0, 0); STAGE(t + 5, 1, 1);
        QKT(2, sA0, sA1, bA); QKT(3, sB0, sB1, bB);
        SMPV(2, sA0, sA1, bA); SMPV(3, sB0, sB1, bB);
        VMBAR();
    }
    // tiles 60,61 (bufs 0,1); stage 62,63 (bufs 2,3)
    STAGE(62, 2, 2); STAGE(63, 3, 3);
    QKT(0, sA0, sA1, bA); QKT(1, sB0, sB1, bB);
    SMPV(0, sA0, sA1, bA); SMPV(1, sB0, sB1, bB);
    VMBAR();
    // tiles 62,63 (bufs 2,3)
    QKT(2, sA0, sA1, bA); QKT(3, sB0, sB1, bB);
    SMPV(2, sA0, sA1, bA); SMPV(3, sB0, sB1, bB);

    // ---- epilogue: row-sum cross-half combine, O^T/l -> aout [b][s][c] bf16 ----
    float c1 = srun, c2 = srun;
    asm volatile("" : "+v"(c2));
    asm volatile("v_permlane32_swap_b32 %0, %1" : "+v"(c1), "+v"(c2));
    float inv = 1.f / (c1 + c2);
    int b = bh >> 2, h = bh & 3;
    short* ob = aout + ((size_t)b * SLEN + q0 + q32) * CIN + h * HD;
#pragma unroll
    for (int g4 = 0; g4 < 4; ++g4) {
        uint2 st0, st1;
        st0.x = cvt_pk(oacc0[4 * g4 + 0] * inv, oacc0[4 * g4 + 1] * inv);
        st0.y = cvt_pk(oacc0[4 * g4 + 2] * inv, oacc0[4 * g4 + 3] * inv);
        st1.x = cvt_pk(oacc1[4 * g4 + 0] * inv, oacc1[4 * g4 + 1] * inv);
        st1.y = cvt_pk(oacc1[4 * g4 + 2] * inv, oacc1[4 * g4 + 3] * inv);
        *(uint2*)(ob + 8 * g4 + 4 * hi) = st0;
        *(uint2*)(ob + 32 + 8 * g4 + 4 * hi) = st1;
    }
#undef STAGE
#undef VMBAR
#undef QKT
#undef PVKC
#undef SMPV
}

// ---------------- kernel C: proj GEMM + BN + SiLU -> fp32 out ----------------
__launch_bounds__(256)
__global__ void k_proj(const short* __restrict__ aout, const short* __restrict__ wbf,
                       const float* __restrict__ g, const float* __restrict__ be,
                       const float* __restrict__ mu, const float* __restrict__ va,
                       float* __restrict__ out) {
    int wv = threadIdx.x >> 6, l = threadIdx.x & 63, lr = l & 15, lg = l >> 4;
    int b = blockIdx.z;
    int s0 = blockIdx.x * 128 + wv * 32;
    int o0 = blockIdx.y * 64;
    f32x4 acc[2][4] = {};
    const short* aptr = aout + ((size_t)b * SLEN + s0 + lr) * CIN + lg * 8;
    const short* bptr = wbf + (size_t)(o0 + lr) * CIN + lg * 8;
#pragma unroll
    for (int k0 = 0; k0 < CIN; k0 += 32) {
        bf16x8 a0 = *(const bf16x8*)(aptr + k0);
        bf16x8 a1 = *(const bf16x8*)(aptr + 16 * CIN + k0);
#pragma unroll
        for (int oj = 0; oj < 4; oj++) {
            bf16x8 bb = *(const bf16x8*)(bptr + oj * 16 * CIN + k0);
            acc[0][oj] = __builtin_amdgcn_mfma_f32_16x16x32_bf16(a0, bb, acc[0][oj], 0, 0, 0);
            acc[1][oj] = __builtin_amdgcn_mfma_f32_16x16x32_bf16(a1, bb, acc[1][oj], 0, 0, 0);
        }
    }
#pragma unroll
    for (int oj = 0; oj < 4; oj++) {
        int o = o0 + oj * 16 + lr;
        float sc = g[o] * rsqrtf(va[o] + 1e-5f);
        float sh = be[o] - mu[o] * sc;
#pragma unroll
        for (int qi = 0; qi < 2; qi++) {
            float4 st;
            float* stp = &st.x;
#pragma unroll
            for (int i = 0; i < 4; i++) {
                float y = acc[qi][oj][i] * sc + sh;
                stp[i] = y / (1.f + __expf(-y));
            }
            int s = s0 + qi * 16 + lg * 4;
            *reinterpret_cast<float4*>(out + ((size_t)b * CIN + o) * SLEN + s) = st;
        }
    }
}

extern "C" void kernel_launch(void* const* d_in, const int* in_sizes, int n_in,
                              void* d_out, int out_size, void* d_ws, size_t ws_size,
                              hipStream_t stream) {
    const float* x    = (const float*)d_in[0];
    const float* qkvw = (const float*)d_in[1];
    const float* qg   = (const float*)d_in[2];
    const float* qbe  = (const float*)d_in[3];
    const float* qmu  = (const float*)d_in[4];
    const float* qva  = (const float*)d_in[5];
    const float* pw   = (const float*)d_in[6];
    const float* pg   = (const float*)d_in[7];
    const float* pbe  = (const float*)d_in[8];
    const float* pmu  = (const float*)d_in[9];
    const float* pva  = (const float*)d_in[10];
    float* out = (float*)d_out;

    char* ws = (char*)d_ws;
    short* xT       = (short*)(ws);                 // 8,388,608 B
    short* qkvw_bf  = (short*)(ws + 8388608);       //   393,216 B
    short* projw_bf = (short*)(ws + 8781824);       //   131,072 B
    short* Qb       = (short*)(ws + 8912896);       // 8,388,608 B
    short* Kb       = (short*)(ws + 17301504);      // 8,388,608 B
    short* Vt       = (short*)(ws + 25690112);      // 8,388,608 B
    short* aout     = (short*)(ws + 34078720);      // 8,388,608 B

    k_convert_w<<<768, 256, 0, stream>>>(qkvw, pw, qkvw_bf, projw_bf);
    k_transpose_x<<<dim3(128, 8, 4), 256, 0, stream>>>(x, xT);
    k_qkv<<<dim3(32, 12, 4), 256, 0, stream>>>(xT, qkvw_bf, qg, qbe, qmu, qva, Qb, Kb, Vt);
    k_attn<<<512, 256, 0, stream>>>(Qb, Kb, Vt, aout);
    k_proj<<<dim3(32, 4, 4), 256, 0, stream>>>(aout, projw_bf, pg, pbe, pmu, pva, out);
}

// Round 10
// 154.256 us; speedup vs baseline: 1.0813x; 1.0385x over previous
//
#include <hip/hip_runtime.h>
#include <hip/hip_bf16.h>
#include <math.h>

#define SLEN 4096
#define CIN 256
#define C3 768
#define NH 4
#define HD 64
#define BATCH 4

typedef __attribute__((ext_vector_type(8))) short bf16x8;
typedef __attribute__((ext_vector_type(4))) float f32x4;
typedef __attribute__((ext_vector_type(16))) float f32x16;

typedef const __attribute__((address_space(1))) void GVoid;
typedef __attribute__((address_space(3))) void LVoid;

__device__ __forceinline__ void gl2lds16(const void* g, void* l) {
    __builtin_amdgcn_global_load_lds((GVoid*)g, (LVoid*)l, 16, 0, 0);
}

__device__ __forceinline__ short f2bf(float f) {
    union { float f; unsigned u; } v; v.f = f;
    unsigned r = v.u + 0x7fff + ((v.u >> 16) & 1);
    return (short)(r >> 16);
}

// single-instruction packed f32->bf16 (RNE) — no builtin on gfx950, inline asm per T12
__device__ __forceinline__ unsigned cvt_pk(float lo, float hi) {
    unsigned r;
    asm("v_cvt_pk_bf16_f32 %0, %1, %2" : "=v"(r) : "v"(lo), "v"(hi));
    return r;
}

// ---------------- kernel W: convert weights to bf16 ----------------
__global__ void k_convert_w(const float* __restrict__ qkvw, const float* __restrict__ projw,
                            short* __restrict__ qkvw_bf, short* __restrict__ projw_bf) {
    int i = blockIdx.x * 256 + threadIdx.x;
    if (i < C3 * CIN) qkvw_bf[i] = f2bf(qkvw[i]);
    if (i < CIN * CIN) projw_bf[i] = f2bf(projw[i]);
}

// ---------------- kernel A: fused transpose + QKV GEMM + BN + SiLU ----------------
// Reads x [b][c][s] fp32 directly (coalesced float4), stages 32k x 128s chunks as f32
// in LDS, assembles bf16 A-fragments via transposed ds_read_b32 + v_cvt_pk_bf16_f32.
// Q,K: [bh][s][d]; Vt: [bh][d][s]. Q pre-scaled by hd^-0.5 * log2(e).
__launch_bounds__(256)
__global__ void k_qkv(const float* __restrict__ x, const short* __restrict__ wbf,
                      const float* __restrict__ g, const float* __restrict__ be,
                      const float* __restrict__ mu, const float* __restrict__ va,
                      short* __restrict__ Q, short* __restrict__ Kb, short* __restrict__ Vt) {
    __shared__ __align__(16) float xt[32][136];   // [k-chunk][s], pad 136 keeps 16B rows
    int wv = threadIdx.x >> 6, l = threadIdx.x & 63, lr = l & 15, lg = l >> 4;
    int b = blockIdx.z;
    int sblk = blockIdx.x * 128;
    int s0 = sblk + wv * 32;
    int o0 = blockIdx.y * 64;

    // staging geometry: thread covers row c = tid>>3, 4 float4 segments
    int tc = threadIdx.x >> 3;
    int tg = threadIdx.x & 7;
    const float* xsrc = x + ((size_t)b * CIN + tc) * SLEN + sblk + tg * 4;

    f32x4 acc[2][4] = {};
    const short* bptr = wbf + (size_t)(o0 + lr) * CIN + lg * 8;
    const float* xrd0 = &xt[lg * 8][wv * 32 + 0 * 16 + lr];
    const float* xrd1 = &xt[lg * 8][wv * 32 + 1 * 16 + lr];

#pragma unroll
    for (int ch = 0; ch < 8; ++ch) {
        int k0 = ch * 32;
        __syncthreads();
        // stage chunk: x[b][k0 + tc][sblk .. sblk+127] -> xt[tc][s]
        const float* xs = xsrc + (size_t)k0 * SLEN;
#pragma unroll
        for (int j = 0; j < 4; ++j) {
            float4 v = *reinterpret_cast<const float4*>(xs + j * 32);
            *reinterpret_cast<float4*>(&xt[tc][tg * 4 + j * 32]) = v;
        }
        __syncthreads();

        // A-fragments: transposed reads + cvt_pk
        union { bf16x8 v; unsigned u[4]; } a0, a1;
#pragma unroll
        for (int p = 0; p < 4; ++p) {
            a0.u[p] = cvt_pk(xrd0[(2 * p) * 136], xrd0[(2 * p + 1) * 136]);
            a1.u[p] = cvt_pk(xrd1[(2 * p) * 136], xrd1[(2 * p + 1) * 136]);
        }
#pragma unroll
        for (int oj = 0; oj < 4; oj++) {
            bf16x8 bb = *(const bf16x8*)(bptr + oj * 16 * CIN + k0);
            acc[0][oj] = __builtin_amdgcn_mfma_f32_16x16x32_bf16(a0.v, bb, acc[0][oj], 0, 0, 0);
            acc[1][oj] = __builtin_amdgcn_mfma_f32_16x16x32_bf16(a1.v, bb, acc[1][oj], 0, 0, 0);
        }
    }

    int which = o0 >> 8;          // uniform per block
    int h = (o0 & 255) >> 6;      // uniform per block
    int bh = b * NH + h;
    const float QSC = 0.125f * 1.44269504088896f;
#pragma unroll
    for (int oj = 0; oj < 4; oj++) {
        int o = o0 + oj * 16 + lr;
        float sc = g[o] * rsqrtf(va[o] + 1e-5f);
        float sh = be[o] - mu[o] * sc;
        int d = o & 63;
#pragma unroll
        for (int qi = 0; qi < 2; qi++) {
#pragma unroll
            for (int i = 0; i < 4; i++) {
                float y = acc[qi][oj][i] * sc + sh;
                float z = y / (1.f + __expf(-y));
                int s = s0 + qi * 16 + lg * 4 + i;
                if (which == 0) {
                    Q[((size_t)bh * SLEN + s) * HD + d] = f2bf(z * QSC);
                } else if (which == 1) {
                    Kb[((size_t)bh * SLEN + s) * HD + d] = f2bf(z);
                } else {
                    Vt[((size_t)bh * HD + d) * SLEN + s] = f2bf(z);
                }
            }
        }
    }
}

// ---------------- kernel ATTN: flash attention, pipelined swapped-QK^T ----
// (round-6 structure, best measured: 95.2 us)
// 4 waves/block, 32 q-rows/wave, KVBLK=64. K 2-buf @ lds+0, V 4-buf @ lds+16384.
// Staging via global_load_lds width=16: linear LDS dest + PRE-SWIZZLED per-lane global
// source. One vmcnt(0)+barrier per tile. XCD-aware decode: XCD k owns bh {2k,2k+1}.
// S^T = mfma_32x32x16(K, Q): lane holds 32 P values for q = lane&31.
__launch_bounds__(256, 2)
__global__ void k_attn(const short* __restrict__ Q, const short* __restrict__ Kg,
                       const short* __restrict__ Vg, short* __restrict__ aout) {
    __shared__ __align__(16) char lds[16384 + 32768];
    int tid = threadIdx.x;
    int wv = tid >> 6, l = tid & 63;
    int q32 = l & 31;
    int hi  = l >> 5;

    int bid = blockIdx.x;
    int xcd = bid & 7, slot = bid >> 3;
    int bh = 2 * xcd + (slot & 1);
    int q0 = (slot >> 1) * 128 + wv * 32;

    const short* kg = Kg + (size_t)bh * SLEN * HD;
    const short* vg = Vg + (size_t)bh * HD * SLEN;

    bf16x8 qf[4];
    {
        const short* qb = Q + ((size_t)bh * SLEN + q0 + q32) * HD + hi * 8;
        qf[0] = *(const bf16x8*)(qb);
        qf[1] = *(const bf16x8*)(qb + 16);
        qf[2] = *(const bf16x8*)(qb + 32);
        qf[3] = *(const bf16x8*)(qb + 48);
    }

    bf16x8 ones;
#pragma unroll
    for (int e = 0; e < 8; ++e) ones[e] = (short)0x3F80;

    f32x16 oacc0 = {}, oacc1 = {}, sacc = {};
    float mrun = 0.0f, bA = 0.0f, bB = 0.0f;

    int colsw = (((l & 7) ^ (l >> 3)) << 4);
    const char* kgB = (const char*)kg;
    const char* vgB = (const char*)vg;
    int ksrc = (wv * 16 + (l >> 3)) * 128 + colsw;
    int vsrc = (wv * 16 + (l >> 3)) * 8192 + colsw;
    int wdst = wv * 2048;

#define STAGE(T, KB, VB) do { \
    gl2lds16(kgB + (size_t)(T) * 8192 + ksrc,          lds + (KB) * 8192 + wdst); \
    gl2lds16(kgB + (size_t)(T) * 8192 + ksrc + 1024,   lds + (KB) * 8192 + wdst + 1024); \
    gl2lds16(vgB + (size_t)(T) * 128 + vsrc,           lds + 16384 + (VB) * 8192 + wdst); \
    gl2lds16(vgB + (size_t)(T) * 128 + vsrc + 65536,   lds + 16384 + (VB) * 8192 + wdst + 1024); \
} while (0)

#define VMBAR() do { \
    asm volatile("s_waitcnt vmcnt(0) lgkmcnt(0)" ::: "memory"); \
    __builtin_amdgcn_s_barrier(); \
    asm volatile("" ::: "memory"); \
} while (0)

    int swz = (l & 7) << 4;
    int a0 = q32 * 128 + ((0 * 32 + hi * 16) ^ swz);
    int a1 = q32 * 128 + ((1 * 32 + hi * 16) ^ swz);
    int a2 = q32 * 128 + ((2 * 32 + hi * 16) ^ swz);
    int a3 = q32 * 128 + ((3 * 32 + hi * 16) ^ swz);

#define QKT(KB, D0, D1, BSET) do { \
    BSET = mrun; \
    float nb_ = -mrun; \
    _Pragma("unroll") for (int r_ = 0; r_ < 16; ++r_) { D0[r_] = nb_; D1[r_] = nb_; } \
    __builtin_amdgcn_s_setprio(1); \
    { \
        bf16x8 k0_, k1_; \
        k0_ = *(const bf16x8*)(lds + a0 + (KB) * 8192); \
        k1_ = *(const bf16x8*)(lds + a0 + (KB) * 8192 + 4096); \
        D0 = __builtin_amdgcn_mfma_f32_32x32x16_bf16(k0_, qf[0], D0, 0, 0, 0); \
        D1 = __builtin_amdgcn_mfma_f32_32x32x16_bf16(k1_, qf[0], D1, 0, 0, 0); \
        k0_ = *(const bf16x8*)(lds + a1 + (KB) * 8192); \
        k1_ = *(const bf16x8*)(lds + a1 + (KB) * 8192 + 4096); \
        D0 = __builtin_amdgcn_mfma_f32_32x32x16_bf16(k0_, qf[1], D0, 0, 0, 0); \
        D1 = __builtin_amdgcn_mfma_f32_32x32x16_bf16(k1_, qf[1], D1, 0, 0, 0); \
        k0_ = *(const bf16x8*)(lds + a2 + (KB) * 8192); \
        k1_ = *(const bf16x8*)(lds + a2 + (KB) * 8192 + 4096); \
        D0 = __builtin_amdgcn_mfma_f32_32x32x16_bf16(k0_, qf[2], D0, 0, 0, 0); \
        D1 = __builtin_amdgcn_mfma_f32_32x32x16_bf16(k1_, qf[2], D1, 0, 0, 0); \
        k0_ = *(const bf16x8*)(lds + a3 + (KB) * 8192); \
        k1_ = *(const bf16x8*)(lds + a3 + (KB) * 8192 + 4096); \
        D0 = __builtin_amdgcn_mfma_f32_32x32x16_bf16(k0_, qf[3], D0, 0, 0, 0); \
        D1 = __builtin_amdgcn_mfma_f32_32x32x16_bf16(k1_, qf[3], D1, 0, 0, 0); \
    } \
    __builtin_amdgcn_s_setprio(0); \
} while (0)

#define PVKC(AK, SV, BASE, VB) do { \
    unsigned A0_ = cvt_pk(SV[(BASE) + 0], SV[(BASE) + 1]); \
    unsigned A1_ = cvt_pk(SV[(BASE) + 2], SV[(BASE) + 3]); \
    unsigned A2_ = cvt_pk(SV[(BASE) + 4], SV[(BASE) + 5]); \
    unsigned A3_ = cvt_pk(SV[(BASE) + 6], SV[(BASE) + 7]); \
    asm volatile("v_permlane32_swap_b32 %0, %1" : "+v"(A0_), "+v"(A2_)); \
    asm volatile("v_permlane32_swap_b32 %0, %1" : "+v"(A1_), "+v"(A3_)); \
    union { bf16x8 v; unsigned u[4]; } pf_; \
    pf_.u[0] = A0_; pf_.u[1] = A1_; pf_.u[2] = A2_; pf_.u[3] = A3_; \
    bf16x8 v0_ = *(const bf16x8*)(lds + (AK) + 16384 + (VB) * 8192); \
    bf16x8 v1_ = *(const bf16x8*)(lds + (AK) + 16384 + (VB) * 8192 + 4096); \
    oacc0 = __builtin_amdgcn_mfma_f32_32x32x16_bf16(v0_, pf_.v, oacc0, 0, 0, 0); \
    oacc1 = __builtin_amdgcn_mfma_f32_32x32x16_bf16(v1_, pf_.v, oacc1, 0, 0, 0); \
    sacc  = __builtin_amdgcn_mfma_f32_32x32x16_bf16(ones, pf_.v, sacc, 0, 0, 0); \
} while (0)

#define SMPV(VB, S0, S1, BSET) do { \
    float pa_ = S0[0], pb_ = S0[8], pc_ = S1[0], pd_ = S1[8]; \
    _Pragma("unroll") for (int r_ = 1; r_ < 8; ++r_) { \
        pa_ = fmaxf(pa_, S0[r_]); pb_ = fmaxf(pb_, S0[8 + r_]); \
        pc_ = fmaxf(pc_, S1[r_]); pd_ = fmaxf(pd_, S1[8 + r_]); \
    } \
    float pms_ = fmaxf(fmaxf(pa_, pb_), fmaxf(pc_, pd_)); \
    float c1_ = pms_, c2_ = pms_; \
    asm volatile("" : "+v"(c2_)); /* force distinct register */ \
    asm volatile("v_permlane32_swap_b32 %0, %1" : "+v"(c1_), "+v"(c2_)); \
    pms_ = fmaxf(c1_, c2_); \
    float db_ = mrun - (BSET); \
    if (!__all(pms_ <= db_ + 10.0f)) { \
        float mn_ = fmaxf(mrun, pms_ + (BSET)); \
        float al_ = __builtin_amdgcn_exp2f(mrun - mn_); \
        _Pragma("unroll") for (int r_ = 0; r_ < 16; ++r_) { oacc0[r_] *= al_; oacc1[r_] *= al_; } \
        sacc[0] *= al_; \
        mrun = mn_; db_ = mn_ - (BSET); \
    } \
    if (__all(db_ == 0.0f)) { \
        _Pragma("unroll") for (int r_ = 0; r_ < 16; ++r_) { \
            S0[r_] = __builtin_amdgcn_exp2f(S0[r_]); \
            S1[r_] = __builtin_amdgcn_exp2f(S1[r_]); \
        } \
    } else { \
        _Pragma("unroll") for (int r_ = 0; r_ < 16; ++r_) { \
            S0[r_] = __builtin_amdgcn_exp2f(S0[r_] - db_); \
            S1[r_] = __builtin_amdgcn_exp2f(S1[r_] - db_); \
        } \
    } \
    __builtin_amdgcn_s_setprio(1); \
    PVKC(a0, S0, 0, VB); \
    PVKC(a1, S0, 8, VB); \
    PVKC(a2, S1, 0, VB); \
    PVKC(a3, S1, 8, VB); \
    __builtin_amdgcn_s_setprio(0); \
} while (0)

    f32x16 sA0, sA1, sB0, sB1;

    // prologue: stage 0; drain; stage 1 + QK(0); drain
    STAGE(0, 0, 0);
    VMBAR();
    STAGE(1, 1, 1);
    QKT(0, sA0, sA1, bA);
    VMBAR();

    // steady state: tiles 1..60, unroll 4 (all buffer indices literal)
    for (int j = 0; j < 15; ++j) {
        STAGE(4 * j + 2, 0, 2); QKT(1, sB0, sB1, bB); SMPV(0, sA0, sA1, bA); VMBAR();
        STAGE(4 * j + 3, 1, 3); QKT(0, sA0, sA1, bA); SMPV(1, sB0, sB1, bB); VMBAR();
        STAGE(4 * j + 4, 0, 0); QKT(1, sB0, sB1, bB); SMPV(2, sA0, sA1, bA); VMBAR();
        STAGE(4 * j + 5, 1, 1); QKT(0, sA0, sA1, bA); SMPV(3, sB0, sB1, bB); VMBAR();
    }
    // t = 61
    STAGE(62, 0, 2); QKT(1, sB0, sB1, bB); SMPV(0, sA0, sA1, bA); VMBAR();
    // t = 62
    STAGE(63, 1, 3); QKT(0, sA0, sA1, bA); SMPV(1, sB0, sB1, bB); VMBAR();
    // t = 63
    QKT(1, sB0, sB1, bB); SMPV(2, sA0, sA1, bA);
    SMPV(3, sB0, sB1, bB);

    // ---- epilogue: O^T/l -> aout [b][s][c] bf16 ----
    float inv = 1.f / sacc[0];
    int b = bh >> 2, h = bh & 3;
    short* ob = aout + ((size_t)b * SLEN + q0 + q32) * CIN + h * HD;
#pragma unroll
    for (int g4 = 0; g4 < 4; ++g4) {
        uint2 st0, st1;
        st0.x = cvt_pk(oacc0[4 * g4 + 0] * inv, oacc0[4 * g4 + 1] * inv);
        st0.y = cvt_pk(oacc0[4 * g4 + 2] * inv, oacc0[4 * g4 + 3] * inv);
        st1.x = cvt_pk(oacc1[4 * g4 + 0] * inv, oacc1[4 * g4 + 1] * inv);
        st1.y = cvt_pk(oacc1[4 * g4 + 2] * inv, oacc1[4 * g4 + 3] * inv);
        *(uint2*)(ob + 8 * g4 + 4 * hi) = st0;
        *(uint2*)(ob + 32 + 8 * g4 + 4 * hi) = st1;
    }
#undef STAGE
#undef VMBAR
#undef QKT
#undef PVKC
#undef SMPV
}

// ---------------- kernel C: proj GEMM + BN + SiLU -> fp32 out ----------------
__launch_bounds__(256)
__global__ void k_proj(const short* __restrict__ aout, const short* __restrict__ wbf,
                       const float* __restrict__ g, const float* __restrict__ be,
                       const float* __restrict__ mu, const float* __restrict__ va,
                       float* __restrict__ out) {
    int wv = threadIdx.x >> 6, l = threadIdx.x & 63, lr = l & 15, lg = l >> 4;
    int b = blockIdx.z;
    int s0 = blockIdx.x * 128 + wv * 32;
    int o0 = blockIdx.y * 64;
    f32x4 acc[2][4] = {};
    const short* aptr = aout + ((size_t)b * SLEN + s0 + lr) * CIN + lg * 8;
    const short* bptr = wbf + (size_t)(o0 + lr) * CIN + lg * 8;
#pragma unroll
    for (int k0 = 0; k0 < CIN; k0 += 32) {
        bf16x8 a0 = *(const bf16x8*)(aptr + k0);
        bf16x8 a1 = *(const bf16x8*)(aptr + 16 * CIN + k0);
#pragma unroll
        for (int oj = 0; oj < 4; oj++) {
            bf16x8 bb = *(const bf16x8*)(bptr + oj * 16 * CIN + k0);
            acc[0][oj] = __builtin_amdgcn_mfma_f32_16x16x32_bf16(a0, bb, acc[0][oj], 0, 0, 0);
            acc[1][oj] = __builtin_amdgcn_mfma_f32_16x16x32_bf16(a1, bb, acc[1][oj], 0, 0, 0);
        }
    }
#pragma unroll
    for (int oj = 0; oj < 4; oj++) {
        int o = o0 + oj * 16 + lr;
        float sc = g[o] * rsqrtf(va[o] + 1e-5f);
        float sh = be[o] - mu[o] * sc;
#pragma unroll
        for (int qi = 0; qi < 2; qi++) {
            float4 st;
            float* stp = &st.x;
#pragma unroll
            for (int i = 0; i < 4; i++) {
                float y = acc[qi][oj][i] * sc + sh;
                stp[i] = y / (1.f + __expf(-y));
            }
            int s = s0 + qi * 16 + lg * 4;
            *reinterpret_cast<float4*>(out + ((size_t)b * CIN + o) * SLEN + s) = st;
        }
    }
}

extern "C" void kernel_launch(void* const* d_in, const int* in_sizes, int n_in,
                              void* d_out, int out_size, void* d_ws, size_t ws_size,
                              hipStream_t stream) {
    const float* x    = (const float*)d_in[0];
    const float* qkvw = (const float*)d_in[1];
    const float* qg   = (const float*)d_in[2];
    const float* qbe  = (const float*)d_in[3];
    const float* qmu  = (const float*)d_in[4];
    const float* qva  = (const float*)d_in[5];
    const float* pw   = (const float*)d_in[6];
    const float* pg   = (const float*)d_in[7];
    const float* pbe  = (const float*)d_in[8];
    const float* pmu  = (const float*)d_in[9];
    const float* pva  = (const float*)d_in[10];
    float* out = (float*)d_out;

    char* ws = (char*)d_ws;
    short* qkvw_bf  = (short*)(ws);                 //   393,216 B
    short* projw_bf = (short*)(ws + 393216);        //   131,072 B
    short* Qb       = (short*)(ws + 524288);        // 8,388,608 B
    short* Kb       = (short*)(ws + 8912896);       // 8,388,608 B
    short* Vt       = (short*)(ws + 17301504);      // 8,388,608 B
    short* aout     = (short*)(ws + 25690112);      // 8,388,608 B

    k_convert_w<<<768, 256, 0, stream>>>(qkvw, pw, qkvw_bf, projw_bf);
    k_qkv<<<dim3(32, 12, 4), 256, 0, stream>>>(x, qkvw_bf, qg, qbe, qmu, qva, Qb, Kb, Vt);
    k_attn<<<512, 256, 0, stream>>>(Qb, Kb, Vt, aout);
    k_proj<<<dim3(32, 4, 4), 256, 0, stream>>>(aout, projw_bf, pg, pbe, pmu, pva, out);
}